// Round 10
// baseline (65.812 us; speedup 1.0000x reference)
//
#include <hip/hip_runtime.h>
#include <stdint.h>

#define HH 224
#define WW 224
#define NSEAM 7
#define BWIDTH 5
#define BB 256
#define KK 64

#define T0STRIDE 2465            // dir0 per-band stride (224*11 + 1 pad word)
#define T1BASE   17255           // = 7*T0STRIDE
#define T1PSTR   2475            // dir1 per-band stride (11 rows * 225)

// DPP helpers (ctrl must be literal): row_shr:1=0x111 (dst[i]=src[i-1]),
// row_shl:1=0x101 (dst[i]=src[i+1]), row_ror:N=0x120+N. Rows = 16 lanes.
#define DPPF_OLD(old, src, ctrl) \
    __int_as_float(__builtin_amdgcn_update_dpp(__float_as_int(old), __float_as_int(src), ctrl, 0xF, 0xF, false))
#define DPPF_Z(src, ctrl) \
    __int_as_float(__builtin_amdgcn_update_dpp(0, __float_as_int(src), ctrl, 0xF, 0xF, true))
#define DPPI_Z(src, ctrl) \
    __builtin_amdgcn_update_dpp(0, (int)(src), ctrl, 0xF, 0xF, true)

// ---------------------------------------------------------------------------
// FUSED kernel v3: one 1024-thread block (16 waves) per image.
//  Stage:  all 16 waves cooperatively copy the 14 band tiles (138 KB) into
//          LDS at near-BW (float4 loads, ~10/thread) -> DP never touches HBM.
//  Phase A (tid<224): 14 seam DPs from LDS; choice packing via 2 ballots
//          (replaces the serial 4-DPP OR-chain and its hazard nops).
//  Phase B (all 1024): label walk, thread=(x, 56-row chunk); one v-compare +
//          one h-compare per pixel; run-length flush -> packed u64 LDS atomic.
//  Phase C: in-block centroid finalize.
// Exact reference semantics: DP candidates [jm,j,jp] strict-< first-min,
// final argmin first-min; centroid sums exact in f32 (fields cnt:22/sy:21/
// sx:21, carry-free by region-size bounds; all integers < 2^22).
// ---------------------------------------------------------------------------
__global__ __launch_bounds__(1024) void fused_kernel(const float* __restrict__ g,
                                                     float* __restrict__ out) {
    __shared__ float    gtile[34580];     // dir0 tiles then dir1 tiles, 138.3KB
    __shared__ uint32_t ch[14][225];      // per-row packed sel bits (b0|b1<<16)
    __shared__ unsigned char pv8[HH][8];  // vertical seams: pv8[y][p] = column
    __shared__ unsigned char ph8[8][HH];  // horizontal seams: ph8[p][x] = row
    __shared__ unsigned long long acc[KK];

    const int tid = threadIdx.x;
    const int b   = blockIdx.x;
    if (tid < KK) acc[tid] = 0ull;

    const float* gb = g + (size_t)b * (HH * WW);

    // ---------------- Stage: band tiles -> LDS (all 16 waves) --------------
    // dir0: 7 col-bands; per row 4 aligned float4 covering cols [28p+20,28p+36)
    for (int i = tid; i < NSEAM * HH * 4; i += 1024) {
        int p = i / (HH * 4);
        int rem = i - p * (HH * 4);
        int r = rem >> 2, q = rem & 3;
        int col0 = 28 * p + 20 + 4 * q;               // 16B-aligned
        float4 v = *reinterpret_cast<const float4*>(gb + r * WW + col0);
        int cb = 4 * q - 3;                           // c for lane e=0
        float vv[4] = {v.x, v.y, v.z, v.w};
#pragma unroll
        for (int e = 0; e < 4; ++e) {
            int c = cb + e;
            if (0 <= c && c < 11) gtile[p * T0STRIDE + r * 11 + c] = vv[e];
        }
    }
    // dir1: 7 row-bands; 11 full rows each, row-contiguous float4
    for (int i = tid; i < NSEAM * 11 * 56; i += 1024) {
        int p = i / (11 * 56);
        int rem = i - p * (11 * 56);
        int q = rem / 56, c4 = rem - q * 56;
        float4 v = *reinterpret_cast<const float4*>(gb + (28 * p + 23 + q) * WW + 4 * c4);
        int o = T1BASE + p * T1PSTR + q * 225 + 4 * c4;
        gtile[o] = v.x; gtile[o + 1] = v.y; gtile[o + 2] = v.z; gtile[o + 3] = v.w;
    }
    __syncthreads();

    // ---------------- Phase A: 14 DPs from LDS (threads 0..223) ------------
    if (tid < 14 * 16) {
        const int j    = tid & 15;
        const int grp  = tid >> 4;              // 0..13
        const int dir  = grp / 7;
        const int p    = grp % 7;
        const int band0 = 28 * (p + 1) - BWIDTH;
        const int jc   = (j > 10) ? 10 : j;     // clamp junk lanes' reads
        const int lbase = (dir == 0) ? (p * T0STRIDE + jc)
                                     : (T1BASE + p * T1PSTR + jc * 225);
        const int lstep = (dir == 0) ? 11 : 1;
        const int shb  = tid & 48;              // this group's ballot slice
        const int sel0 = (j == 0) ? 1 : 0;      // sel when jm candidate wins

        float tbA[16], tbB[16], cost;

#define LOADT(BUF, c)                                                       \
    _Pragma("unroll")                                                       \
    for (int rr = 0; rr < 16; ++rr) BUF[rr] = gtile[lbase + ((c) * 16 + rr) * lstep];

#define ROWSTEP(BUF, rr, rbase)                                             \
    {                                                                       \
        float pm  = DPPF_OLD(cost, cost, 0x111); /* prev[j-1], lane0 keeps own */  \
        float ppv = DPPF_OLD(cost, cost, 0x101); /* prev[j+1], lane15 keeps own */ \
        ppv = (j >= 10) ? cost : ppv;            /* clip at j=10 */                \
        float best = fminf(fminf(pm, cost), ppv);                           \
        int sel = (pm == best) ? sel0 : ((cost == best) ? 1 : 2);           \
        cost = best - BUF[rr];                                              \
        unsigned long long b0 = __ballot(sel & 1);                          \
        unsigned long long b1 = __ballot(sel & 2);                          \
        if (j == 0) ch[grp][(rbase) + rr] =                                 \
            (uint32_t)(((b0 >> shb) & 0xFFFFull) |                          \
                       (((b1 >> shb) & 0xFFFFull) << 16));                  \
    }

#define PROCC(BUF, cbase)                                                   \
    _Pragma("unroll")                                                       \
    for (int rr = 0; rr < 16; ++rr) ROWSTEP(BUF, rr, (cbase) * 16)

        LOADT(tbA, 0);
        LOADT(tbB, 1);
        cost = -tbA[0];
#pragma unroll
        for (int rr = 1; rr < 16; ++rr) ROWSTEP(tbA, rr, 0);
        LOADT(tbA, 2);
        PROCC(tbB, 1);
        LOADT(tbB, 3);

#pragma unroll 1
        for (int c2 = 2; c2 <= 12; c2 += 2) {
            PROCC(tbA, c2);
            if (c2 + 2 < 14) LOADT(tbA, c2 + 2);
            PROCC(tbB, c2 + 1);
            if (c2 + 3 < 14) LOADT(tbB, c2 + 3);
        }

        // final argmin across 11 lanes, first-min == lexicographic min
        float rc = (j <= 10) ? cost : INFINITY;
        int   ri = (j <= 10) ? j : 15;
#define REDSTEP(ctrl)                                                        \
        {                                                                    \
            float oc = DPPF_Z(rc, ctrl);                                     \
            int   oi = DPPI_Z(ri, ctrl);                                     \
            bool t = (oc < rc) || (oc == rc && oi < ri);                     \
            rc = t ? oc : rc; ri = t ? oi : ri;                              \
        }
        REDSTEP(0x128) REDSTEP(0x124) REDSTEP(0x122) REDSTEP(0x121)
#undef REDSTEP

        int pos = ri;
        const bool wr = (j == 0);
        if (wr) {
            if (dir == 0) pv8[HH - 1][p] = (unsigned char)(band0 + pos);
            else          ph8[p][HH - 1] = (unsigned char)(band0 + pos);
        }

        // backtrack: broadcast LDS reads prefetched per chunk; ~4 VALU/row
#pragma unroll 1
        for (int c = 13; c >= 0; --c) {
            uint32_t w[16];
#pragma unroll
            for (int rr = 0; rr < 16; ++rr) w[rr] = ch[grp][c * 16 + rr];
#pragma unroll
            for (int rr = 15; rr >= 0; --rr) {
                int r = c * 16 + rr;
                if (r >= 1) {
                    uint32_t ww = w[rr];
                    int sel = (int)((ww >> pos) & 1u) | (int)((ww >> (pos + 15)) & 2u);
                    pos += sel - 1;
                    if (wr) {
                        if (dir == 0) pv8[r - 1][p] = (unsigned char)(band0 + pos);
                        else          ph8[p][r - 1] = (unsigned char)(band0 + pos);
                    }
                }
            }
        }

#undef LOADT
#undef PROCC
#undef ROWSTEP
    }

    __syncthreads();

    // ---------------- Phase B: labels + centroid partials ------------------
    // thread = (x = tid&255, chunk = tid>>8); each walks 56 rows. Seam p lies
    // in [28p+23, 28p+33] (disjoint bands): one v-compare + one h-compare.
    const int x  = tid & 255;
    const int y0 = (tid >> 8) * (HH / 4);
    const int y1 = y0 + (HH / 4);
    if (x < WW) {
        int basev = 0, kv = 0, inv = 0;
        if (x >= 23) {
            int q = x - 23, k = q / 28, r = q - k * 28;
            if (k > 6) basev = 7;
            else { inv = (r <= 10) ? 1 : 0; basev = k + (r > 10 ? 1 : 0); kv = k; }
        }
        float* mb = out + (size_t)BB * KK * 2 + (size_t)b * HH * WW;
        int cur = -1, ys = y0;
        for (int y = y0; y < y1; ++y) {
            int bh = 0, kh = 0, ih = 0;       // wave-uniform (y loop-uniform)
            if (y >= 23) {
                int q = y - 23, k = q / 28, r = q - k * 28;
                if (k > 6) bh = 7;
                else { ih = (r <= 10) ? 1 : 0; bh = k + (r > 10 ? 1 : 0); kh = k; }
            }
            int vl = basev + ((inv && (int)pv8[y][kv] <= x) ? 1 : 0);
            int hl = bh;
            if (ih) hl += ((int)ph8[kh][x] <= y) ? 1 : 0;
            int lab = vl + 8 * hl;
            mb[y * WW + x] = (float)lab;
            if (lab != cur) {
                if (cur >= 0) {
                    unsigned cnt = (unsigned)(y - ys);
                    unsigned sy  = (unsigned)((ys + y - 1) * (y - ys) / 2);
                    unsigned sx  = (unsigned)x * cnt;
                    atomicAdd(&acc[cur], ((unsigned long long)cnt << 42) |
                                         ((unsigned long long)sy << 21) |
                                         (unsigned long long)sx);
                }
                cur = lab; ys = y;
            }
        }
        {
            unsigned cnt = (unsigned)(y1 - ys);
            unsigned sy  = (unsigned)((ys + y1 - 1) * (y1 - ys) / 2);
            unsigned sx  = (unsigned)x * cnt;
            atomicAdd(&acc[cur], ((unsigned long long)cnt << 42) |
                                 ((unsigned long long)sy << 21) |
                                 (unsigned long long)sx);
        }
    }
    __syncthreads();

    // ---------------- Phase C: finalize centroids --------------------------
    if (tid < KK) {
        unsigned long long sv = acc[tid];
        float cnt = (float)(unsigned)(sv >> 42);
        float sy  = (float)(unsigned)((sv >> 21) & 0x1FFFFFu);
        float sx  = (float)(unsigned)(sv & 0x1FFFFFu);
        float c = fmaxf(cnt, 1e-6f);
        float2 r; r.x = sy / c; r.y = sx / c;
        *reinterpret_cast<float2*>(out + (size_t)b * KK * 2 + tid * 2) = r;
    }
}

extern "C" void kernel_launch(void* const* d_in, const int* in_sizes, int n_in,
                              void* d_out, int out_size, void* d_ws, size_t ws_size,
                              hipStream_t stream) {
    const float* g = (const float*)d_in[1];
    float* out = (float*)d_out;
    fused_kernel<<<BB, 1024, 0, stream>>>(g, out);
}

// Round 11
// 57.586 us; speedup vs baseline: 1.1428x; 1.1428x over previous
//
#include <hip/hip_runtime.h>
#include <stdint.h>

#define HH 224
#define WW 224
#define NSEAM 7
#define BWIDTH 5
#define BB 256
#define KK 64
#define YCH 8
#define YROWS (HH / YCH)

// DPP helpers (ctrl must be literal): row_shr:1=0x111 (dst[i]=src[i-1]),
// row_shl:1=0x101 (dst[i]=src[i+1]), row_ror:N=0x120+N. Rows = 16 lanes.
#define DPPF_OLD(old, src, ctrl) \
    __int_as_float(__builtin_amdgcn_update_dpp(__float_as_int(old), __float_as_int(src), ctrl, 0xF, 0xF, false))
#define DPPF_Z(src, ctrl) \
    __int_as_float(__builtin_amdgcn_update_dpp(0, __float_as_int(src), ctrl, 0xF, 0xF, true))
#define DPPI_Z(src, ctrl) \
    __builtin_amdgcn_update_dpp(0, (int)(src), ctrl, 0xF, 0xF, true)

// ---------------------------------------------------------------------------
// Kernel 1: seam DP, 16 lanes per DP. Dir-major mapping (R5-validated):
// gid = dir*1792 + b*7 + p -> dir is block-uniform. KEY CHANGE (R7 counters:
// 21MB @ 830GB/s, request-issue-bound): dir1 loads become 4x float4 per
// chunk (lane j's 16 chunk values are CONTIGUOUS in its band row) -> 256
// requests/chunk/wave instead of 1024 (16 scalar instrs x 64 lines).
// Choice packing via 2 ballots (v3-validated), removing the serial DPP
// OR-chain. Runtime chunk loop (R6), depth-2 A/B register double-buffer.
// Exact reference semantics: candidates [jm,j,jp] strict-< first-min (fminf
// + equality compares in candidate order, absmax=0 since R4), final argmin
// first-min, backtrack via per-row sel bits. Also zeroes gacc.
// ---------------------------------------------------------------------------
__global__ __launch_bounds__(256) void dp_kernel(const float* __restrict__ g,
                                                 int* __restrict__ paths,
                                                 unsigned long long* __restrict__ gacc) {
    __shared__ uint32_t ch[16][226];   // per-row packed sel bits (b0 | b1<<16)
    __shared__ int      pth[16][226];  // backtracked path positions

    {   // zero global centroid accumulators (label kernel runs after us)
        int t = blockIdx.x * 256 + threadIdx.x;
        if (t < BB * KK) gacc[t] = 0ull;
    }

    const int j   = threadIdx.x & 15;
    const int grp = threadIdx.x >> 4;
    const int gid = blockIdx.x * 16 + grp;
    const int dir = gid / (BB * NSEAM);         // block-uniform (1792/16=112)
    const int rem = gid - dir * (BB * NSEAM);
    const int b   = rem / NSEAM;
    const int p   = rem - b * NSEAM;
    const int band0 = 28 * (p + 1) - BWIDTH;
    const int jc  = (j > 10) ? 10 : j;          // clamp junk lanes
    const float* gb  = g + (size_t)b * HH * WW;
    const float* gp0 = gb + band0 + jc;                 // dir0: +row*WW
    const float* gp1 = gb + (size_t)(band0 + jc) * WW;  // dir1: contiguous cols
    const int shb  = threadIdx.x & 48;          // this group's ballot slice
    const int sel0 = (j == 0) ? 1 : 0;          // sel when jm candidate wins

    float bufA[16], bufB[16], cost;

#define LOADC(BUF, c)                                                       \
    if (dir == 0) {                                                         \
        _Pragma("unroll")                                                   \
        for (int rr = 0; rr < 16; ++rr) BUF[rr] = gp0[((c) * 16 + rr) * WW];\
    } else {                                                                \
        const float4* q4 = reinterpret_cast<const float4*>(gp1 + (c) * 16); \
        float4 t0 = q4[0], t1 = q4[1], t2 = q4[2], t3 = q4[3];              \
        BUF[0] = t0.x;  BUF[1] = t0.y;  BUF[2] = t0.z;  BUF[3] = t0.w;      \
        BUF[4] = t1.x;  BUF[5] = t1.y;  BUF[6] = t1.z;  BUF[7] = t1.w;      \
        BUF[8] = t2.x;  BUF[9] = t2.y;  BUF[10] = t2.z; BUF[11] = t2.w;     \
        BUF[12] = t3.x; BUF[13] = t3.y; BUF[14] = t3.z; BUF[15] = t3.w;     \
    }

#define ROWSTEP(BUF, rr, rbase)                                             \
    {                                                                       \
        float pm  = DPPF_OLD(cost, cost, 0x111); /* prev[j-1], lane0 keeps own */  \
        float ppv = DPPF_OLD(cost, cost, 0x101); /* prev[j+1], lane15 keeps own */ \
        ppv = (j >= 10) ? cost : ppv;            /* clip at j=10 */                \
        float best = fminf(fminf(pm, cost), ppv);                           \
        int sel = (pm == best) ? sel0 : ((cost == best) ? 1 : 2);           \
        cost = best - BUF[rr];                                              \
        unsigned long long b0 = __ballot(sel & 1);                          \
        unsigned long long b1 = __ballot(sel & 2);                          \
        if (j == 0) ch[grp][(rbase) + rr] =                                 \
            (uint32_t)(((b0 >> shb) & 0xFFFFull) |                          \
                       (((b1 >> shb) & 0xFFFFull) << 16));                  \
    }

#define PROCC(BUF, cbase)                                                   \
    _Pragma("unroll")                                                       \
    for (int rr = 0; rr < 16; ++rr) ROWSTEP(BUF, rr, (cbase) * 16)

    // prologue: chunk 0 (row-0 init) + chunk 1; loads kept 2 chunks ahead
    LOADC(bufA, 0);
    LOADC(bufB, 1);
    cost = -bufA[0];
#pragma unroll
    for (int rr = 1; rr < 16; ++rr) ROWSTEP(bufA, rr, 0);
    LOADC(bufA, 2);
    PROCC(bufB, 1);
    LOADC(bufB, 3);

#pragma unroll 1
    for (int c2 = 2; c2 <= 12; c2 += 2) {
        PROCC(bufA, c2);
        if (c2 + 2 < 14) LOADC(bufA, c2 + 2);
        PROCC(bufB, c2 + 1);
        if (c2 + 3 < 14) LOADC(bufB, c2 + 3);
    }

    // final argmin across 11 lanes, first-min tie-break == lexicographic min
    float rc = (j <= 10) ? cost : INFINITY;
    int   ri = (j <= 10) ? j : 15;
#define REDSTEP(ctrl)                                                        \
    {                                                                        \
        float oc = DPPF_Z(rc, ctrl);                                         \
        int   oi = DPPI_Z(ri, ctrl);                                         \
        bool t = (oc < rc) || (oc == rc && oi < ri);                         \
        rc = t ? oc : rc; ri = t ? oi : ri;                                  \
    }
    REDSTEP(0x128) REDSTEP(0x124) REDSTEP(0x122) REDSTEP(0x121)
#undef REDSTEP

    int pos = ri;
    if (j == 0) pth[grp][HH - 1] = band0 + pos;

    // backtrack: broadcast LDS reads prefetched per chunk; ~4 VALU/row chain
#pragma unroll 1
    for (int c = 13; c >= 0; --c) {
        uint32_t w[16];
#pragma unroll
        for (int rr = 0; rr < 16; ++rr) w[rr] = ch[grp][c * 16 + rr];
#pragma unroll
        for (int rr = 15; rr >= 0; --rr) {
            int r = c * 16 + rr;
            if (r >= 1) {
                uint32_t ww = w[rr];
                int sel = (int)((ww >> pos) & 1u) | (int)((ww >> (pos + 15)) & 2u);
                pos += sel - 1;
                if (j == 0) pth[grp][r - 1] = band0 + pos;
            }
        }
    }

    // coalesced path write; layout [b][dir*7+p][224]
    int* op = paths + (size_t)(b * 14 + dir * NSEAM + p) * HH;
#pragma unroll 1
    for (int c = 0; c < 14; ++c) op[c * 16 + j] = pth[grp][c * 16 + j];

#undef LOADC
#undef PROCC
#undef ROWSTEP
}

// ---------------------------------------------------------------------------
// Kernel 2: labels + centroid partials. Grid = B*8 (28-row chunks) -> 32
// waves/CU of TLP for the latency-bound walk (R2->R3 scaling evidence).
// Thread = column; run-length flush -> packed u64 LDS atomic per run; block
// partials -> global atomicAdd. Fields: [42..63]=cnt, [21..41]=sum_y,
// [0..20]=sum_x; per-region totals < field capacity, u64 adds carry-free,
// all values integers < 2^22 exact in f32 -> division matches JAX bitwise.
// ---------------------------------------------------------------------------
__global__ __launch_bounds__(256) void label_kernel(const int* __restrict__ paths,
                                                    float* __restrict__ out,
                                                    unsigned long long* __restrict__ gacc) {
    const int b  = blockIdx.x >> 3;
    const int y0 = (blockIdx.x & 7) * YROWS;
    const int y1 = y0 + YROWS;

    __shared__ int vpc[NSEAM][YROWS];
    __shared__ unsigned long long acc[KK];

    const int* pb = paths + (size_t)b * 14 * HH;
    for (int i = threadIdx.x; i < NSEAM * YROWS; i += 256) {
        int q = i / YROWS, r = i - q * YROWS;
        vpc[q][r] = pb[q * HH + y0 + r];
    }
    if (threadIdx.x < KK) acc[threadIdx.x] = 0ull;
    __syncthreads();

    const int x = threadIdx.x;
    if (x < WW) {
        int hx[NSEAM];
#pragma unroll
        for (int q = 0; q < NSEAM; ++q) hx[q] = pb[(NSEAM + q) * HH + x];

        float* mb = out + (size_t)BB * KK * 2 + (size_t)b * HH * WW;
        int cur = -1, ys = y0;
        for (int y = y0; y < y1; ++y) {
            int vl = 0, hl = 0;
#pragma unroll
            for (int q = 0; q < NSEAM; ++q) {
                vl += (vpc[q][y - y0] <= x) ? 1 : 0;
                hl += (hx[q] <= y) ? 1 : 0;
            }
            int lab = vl + 8 * hl;
            mb[y * WW + x] = (float)lab;
            if (lab != cur) {
                if (cur >= 0) {
                    unsigned cnt = (unsigned)(y - ys);
                    unsigned sy  = (unsigned)((ys + y - 1) * (y - ys) / 2);
                    unsigned sx  = (unsigned)x * cnt;
                    atomicAdd(&acc[cur], ((unsigned long long)cnt << 42) |
                                         ((unsigned long long)sy << 21) |
                                         (unsigned long long)sx);
                }
                cur = lab; ys = y;
            }
        }
        {
            unsigned cnt = (unsigned)(y1 - ys);
            unsigned sy  = (unsigned)((ys + y1 - 1) * (y1 - ys) / 2);
            unsigned sx  = (unsigned)x * cnt;
            atomicAdd(&acc[cur], ((unsigned long long)cnt << 42) |
                                 ((unsigned long long)sy << 21) |
                                 (unsigned long long)sx);
        }
    }
    __syncthreads();

    if (threadIdx.x < KK) {
        unsigned long long v = acc[threadIdx.x];
        if (v) atomicAdd(&gacc[(size_t)b * KK + threadIdx.x], v);
    }
}

// ---------------------------------------------------------------------------
// Kernel 3: finalize centroids. 16384 regions; unpack, divide, float2 store.
// ---------------------------------------------------------------------------
__global__ __launch_bounds__(256) void finalize_kernel(const unsigned long long* __restrict__ gacc,
                                                       float* __restrict__ out) {
    int i = blockIdx.x * 256 + threadIdx.x;    // < BB*KK
    unsigned long long sv = gacc[i];
    float cnt = (float)(unsigned)(sv >> 42);
    float sy  = (float)(unsigned)((sv >> 21) & 0x1FFFFFu);
    float sx  = (float)(unsigned)(sv & 0x1FFFFFu);
    float c = fmaxf(cnt, 1e-6f);
    float2 r; r.x = sy / c; r.y = sx / c;
    *reinterpret_cast<float2*>(out + (size_t)i * 2) = r;
}

extern "C" void kernel_launch(void* const* d_in, const int* in_sizes, int n_in,
                              void* d_out, int out_size, void* d_ws, size_t ws_size,
                              hipStream_t stream) {
    const float* g = (const float*)d_in[1];
    float* out = (float*)d_out;
    int* paths = (int*)d_ws;                                   // 3,211,264 B
    unsigned long long* gacc =
        (unsigned long long*)((char*)d_ws + (size_t)BB * 14 * HH * 4);  // 128 KiB

    dp_kernel<<<(BB * 14) / 16, 256, 0, stream>>>(g, paths, gacc);
    label_kernel<<<BB * YCH, 256, 0, stream>>>(paths, out, gacc);
    finalize_kernel<<<(BB * KK) / 256, 256, 0, stream>>>(gacc, out);
}